// Round 6
// baseline (308.964 us; speedup 1.0000x reference)
//
#include <hip/hip_runtime.h>
#include <math.h>

#define Bg   128
#define Ng   256
#define Dg   256
#define Hg   8
#define HDg  32
#define Eg   524288
#define Kg   128
#define BNg  32768
#define SENT 16384   // = Bg*Kg

using bf16x8 = __attribute__((ext_vector_type(8))) short;
using f32x4  = __attribute__((ext_vector_type(4))) float;

// split f32 -> bf16 hi (truncated) + bf16 lo (residual)
__device__ inline void split2(float x, short &h, short &l) {
    unsigned u = __float_as_uint(x);
    h = (short)(u >> 16);
    float hf = __uint_as_float(u & 0xffff0000u);
    float r = x - hf;
    l = (short)(__float_as_uint(r) >> 16);
}
// pack: low 16 = hi bf16, high 16 = lo bf16
__device__ inline unsigned packsplit(float x) {
    unsigned u = __float_as_uint(x);
    float hf = __uint_as_float(u & 0xffff0000u);
    float r = x - hf;
    unsigned lu = __float_as_uint(r);
    return (u >> 16) | (lu & 0xffff0000u);
}
__device__ inline unsigned pack2(short a, short b) {
    return (unsigned)(unsigned short)a | ((unsigned)(unsigned short)b << 16);
}

// ---------------- P1: split x into hi/lo bf16 ----------------
__global__ __launch_bounds__(256) void split_x(
    const float* __restrict__ x, short* __restrict__ xh, short* __restrict__ xl)
{
    size_t i = ((size_t)blockIdx.x * 256 + threadIdx.x) * 8;
    float4 a = *(const float4*)(x + i);
    float4 b = *(const float4*)(x + i + 4);
    float v[8] = {a.x,a.y,a.z,a.w,b.x,b.y,b.z,b.w};
    short h[8], l[8];
    #pragma unroll
    for (int j = 0; j < 8; ++j) split2(v[j], h[j], l[j]);
    uint4 uh, ul;
    uh.x = pack2(h[0],h[1]); uh.y = pack2(h[2],h[3]);
    uh.z = pack2(h[4],h[5]); uh.w = pack2(h[6],h[7]);
    ul.x = pack2(l[0],l[1]); ul.y = pack2(l[2],l[3]);
    ul.z = pack2(l[4],l[5]); ul.w = pack2(l[6],l[7]);
    *(uint4*)(xh + i) = uh;
    *(uint4*)(xl + i) = ul;
}

// ---------------- P2: transpose + split weights: WT[n][k] = W[k][n] ----------
__global__ __launch_bounds__(256) void wprep(
    const float* __restrict__ Wq, const float* __restrict__ Wk,
    const float* __restrict__ Wv, const float* __restrict__ Wo,
    short* __restrict__ WTh, short* __restrict__ WTl)
{
    __shared__ float t[64][65];
    const int bid = blockIdx.x;          // 0..63
    const int mat = bid >> 4;
    const int kt = (bid >> 2) & 3, nt = bid & 3;
    const float* W = (mat==0) ? Wq : (mat==1) ? Wk : (mat==2) ? Wv : Wo;
    const int tid = threadIdx.x;
    const int r = tid >> 2, c4 = tid & 3;
    #pragma unroll
    for (int i = 0; i < 4; ++i) {
        float4 v = *(const float4*)(W + (size_t)(kt*64 + r)*256 + nt*64 + c4*16 + i*4);
        t[r][c4*16 + i*4 + 0] = v.x; t[r][c4*16 + i*4 + 1] = v.y;
        t[r][c4*16 + i*4 + 2] = v.z; t[r][c4*16 + i*4 + 3] = v.w;
    }
    __syncthreads();
    const int n = r, k0 = c4 * 16;
    short hb[16], lb[16];
    #pragma unroll
    for (int i = 0; i < 16; ++i) split2(t[k0 + i][n], hb[i], lb[i]);
    size_t base = (size_t)mat*65536 + (size_t)(nt*64 + n)*256 + kt*64 + k0;
    uint4 uh0, uh1, ul0, ul1;
    uh0.x=pack2(hb[0],hb[1]);  uh0.y=pack2(hb[2],hb[3]);  uh0.z=pack2(hb[4],hb[5]);  uh0.w=pack2(hb[6],hb[7]);
    uh1.x=pack2(hb[8],hb[9]);  uh1.y=pack2(hb[10],hb[11]);uh1.z=pack2(hb[12],hb[13]);uh1.w=pack2(hb[14],hb[15]);
    ul0.x=pack2(lb[0],lb[1]);  ul0.y=pack2(lb[2],lb[3]);  ul0.z=pack2(lb[4],lb[5]);  ul0.w=pack2(lb[6],lb[7]);
    ul1.x=pack2(lb[8],lb[9]);  ul1.y=pack2(lb[10],lb[11]);ul1.z=pack2(lb[12],lb[13]);ul1.w=pack2(lb[14],lb[15]);
    *(uint4*)&WTh[base]     = uh0; *(uint4*)&WTh[base + 8] = uh1;
    *(uint4*)&WTl[base]     = ul0; *(uint4*)&WTl[base + 8] = ul1;
}

// ---------------- K1: QKV projection via 4-term split MFMA -------------------
// Outputs packed-split u32 (hi | lo<<16); Q pre-scaled by 1/sqrt(32).
__global__ __launch_bounds__(256) void qkv_mm(
    const short* __restrict__ xh, const short* __restrict__ xl,
    const short* __restrict__ WTh, const short* __restrict__ WTl,
    const float* __restrict__ bq, const float* __restrict__ bk, const float* __restrict__ bv,
    unsigned* __restrict__ Qp, unsigned* __restrict__ Kp, unsigned* __restrict__ Vp)
{
    const int z = blockIdx.z;
    const float* bias = (z==0) ? bq : (z==1) ? bk : bv;
    unsigned* out     = (z==0) ? Qp : (z==1) ? Kp : Vp;
    const float scale = (z==0) ? 0.17677669529663687f : 1.0f;
    const short* bth = WTh + (size_t)z * 65536;
    const short* btl = WTl + (size_t)z * 65536;
    __shared__ __align__(16) short lds[16384];   // Ah 0 | Al 4096 | Bh 8192 | Bl 12288
    const int tid = threadIdx.x;
    const int lane = tid & 63, w = tid >> 6;
    const int g = lane >> 4, li = lane & 15;
    const int wr = w >> 1, wc = w & 1;
    const int m0 = blockIdx.x * 128, n0 = blockIdx.y * 128;
    f32x4 acc[4][4];
    #pragma unroll
    for (int i = 0; i < 4; ++i)
        #pragma unroll
        for (int j = 0; j < 4; ++j) acc[i][j] = (f32x4){0.f,0.f,0.f,0.f};

    for (int k0 = 0; k0 < 256; k0 += 32) {
        #pragma unroll
        for (int it = 0; it < 2; ++it) {
            int chunk = it*256 + tid;
            int r = chunk >> 2, c = chunk & 3;
            size_t ga = (size_t)(m0 + r)*256 + k0 + c*8;
            size_t gb = (size_t)(n0 + r)*256 + k0 + c*8;
            uint4 vh = *(const uint4*)(xh + ga);
            uint4 vl = *(const uint4*)(xl + ga);
            uint4 wh = *(const uint4*)(bth + gb);
            uint4 wl = *(const uint4*)(btl + gb);
            *(uint4*)&lds[        chunk*8] = vh;
            *(uint4*)&lds[ 4096 + chunk*8] = vl;
            *(uint4*)&lds[ 8192 + chunk*8] = wh;
            *(uint4*)&lds[12288 + chunk*8] = wl;
        }
        __syncthreads();
        bf16x8 ah[4], al[4], bh[4], bl[4];
        #pragma unroll
        for (int i = 0; i < 4; ++i) {
            int row = wr*64 + i*16 + li;
            ah[i] = *(const bf16x8*)&lds[       row*32 + g*8];
            al[i] = *(const bf16x8*)&lds[4096 + row*32 + g*8];
        }
        #pragma unroll
        for (int j = 0; j < 4; ++j) {
            int row = wc*64 + j*16 + li;
            bh[j] = *(const bf16x8*)&lds[ 8192 + row*32 + g*8];
            bl[j] = *(const bf16x8*)&lds[12288 + row*32 + g*8];
        }
        #pragma unroll
        for (int i = 0; i < 4; ++i)
            #pragma unroll
            for (int j = 0; j < 4; ++j) {
                acc[i][j] = __builtin_amdgcn_mfma_f32_16x16x32_bf16(ah[i], bh[j], acc[i][j], 0,0,0);
                acc[i][j] = __builtin_amdgcn_mfma_f32_16x16x32_bf16(ah[i], bl[j], acc[i][j], 0,0,0);
                acc[i][j] = __builtin_amdgcn_mfma_f32_16x16x32_bf16(al[i], bh[j], acc[i][j], 0,0,0);
                acc[i][j] = __builtin_amdgcn_mfma_f32_16x16x32_bf16(al[i], bl[j], acc[i][j], 0,0,0);
            }
        __syncthreads();
    }
    #pragma unroll
    for (int i = 0; i < 4; ++i)
        #pragma unroll
        for (int j = 0; j < 4; ++j)
            #pragma unroll
            for (int r = 0; r < 4; ++r) {
                int m = m0 + wr*64 + i*16 + g*4 + r;
                int c = n0 + wc*64 + j*16 + li;
                int b = m >> 8, nn = m & 255;
                int h = c >> 5, hd = c & 31;
                float val = (acc[i][j][r] + bias[c]) * scale;
                out[((size_t)(b*Hg + h)*Ng + nn)*HDg + hd] = packsplit(val);
            }
}

// ---------------- K2: MFMA flash attention (load-early / write-late) --------
// Packed-split inputs; batched per-wave P; prefetch K/V and dist one chunk
// ahead into registers, LDS-write after compute; one barrier per chunk.
__global__ __launch_bounds__(256, 2) void attn_mfma(
    const unsigned* __restrict__ Qp, const unsigned* __restrict__ Kp,
    const unsigned* __restrict__ Vp, const float* __restrict__ dist,
    unsigned* __restrict__ AOp)
{
    __shared__ short    Khi[2][32][40];     //  5120 B
    __shared__ short    Klo[2][32][40];     //  5120 B
    __shared__ unsigned Vt [2][32][36];     //  9216 B  [buf][d][key] packed
    __shared__ unsigned P32[4][64][36];     // 36864 B  per-wave P (batched)

    const int bh = blockIdx.x;
    const int b  = bh >> 3;
    const int h  = bh & 7;
    const int tid = threadIdx.x;
    const int w = tid >> 6;
    const int lane = tid & 63;
    const int g = lane >> 4;
    const int li = lane & 15;
    const int q0 = w * 64;
    const int skey = tid >> 3, se0 = (tid & 7) * 4;   // staging coords
    const float* dall = dist + (size_t)b*Ng*Ng;

    // Q fragments (already scaled + split in qkv_mm)
    bf16x8 qh[4], ql[4];
    #pragma unroll
    for (int tq = 0; tq < 4; ++tq) {
        const unsigned* qp = Qp + ((size_t)bh * Ng + q0 + tq*16 + li) * HDg + g*8;
        uint4 u0 = *(const uint4*)qp;
        uint4 u1 = *(const uint4*)(qp + 4);
        unsigned uu[8] = {u0.x,u0.y,u0.z,u0.w,u1.x,u1.y,u1.z,u1.w};
        #pragma unroll
        for (int j = 0; j < 8; ++j) {
            qh[tq][j] = (short)(uu[j] & 0xffff);
            ql[tq][j] = (short)(uu[j] >> 16);
        }
    }

    f32x4 dA[4][2], dB[4][2];
    // prologue: dist chunk 0 -> dA; stage K/V chunk 0 -> buf 0
    #pragma unroll
    for (int tq = 0; tq < 4; ++tq)
        #pragma unroll
        for (int tc = 0; tc < 2; ++tc) {
            const float* dp = dall + (size_t)(q0 + tq*16 + g*4)*Ng + tc*16 + li;
            f32x4 s; s[0]=dp[0]; s[1]=dp[Ng]; s[2]=dp[2*Ng]; s[3]=dp[3*Ng];
            dA[tq][tc] = s;
        }
    {
        uint4 kv = *(const uint4*)(Kp + ((size_t)bh*Ng + skey) * HDg + se0);
        uint4 vv = *(const uint4*)(Vp + ((size_t)bh*Ng + skey) * HDg + se0);
        unsigned ka[4] = {kv.x,kv.y,kv.z,kv.w};
        unsigned va[4] = {vv.x,vv.y,vv.z,vv.w};
        #pragma unroll
        for (int i = 0; i < 4; ++i) {
            Khi[0][skey][se0+i] = (short)(ka[i] & 0xffff);
            Klo[0][skey][se0+i] = (short)(ka[i] >> 16);
            Vt [0][se0+i][skey] = va[i];
        }
    }
    __syncthreads();

    f32x4 O[4][2];
    #pragma unroll
    for (int tq=0;tq<4;++tq)
        #pragma unroll
        for (int td=0;td<2;++td) O[tq][td] = (f32x4){0.f,0.f,0.f,0.f};
    float lpart[4][4] = {};

    auto body = [&](int ch, f32x4 (&dcur)[4][2], f32x4 (&dnx)[4][2]) {
        const int cur = ch & 1;
        const bool pref = (ch < 7);
        uint4 kvr, vvr;
        if (pref) {
            // issue next-chunk loads EARLY (regs); consumed after compute
            kvr = *(const uint4*)(Kp + ((size_t)bh*Ng + (ch+1)*32 + skey) * HDg + se0);
            vvr = *(const uint4*)(Vp + ((size_t)bh*Ng + (ch+1)*32 + skey) * HDg + se0);
            const float* dbase = dall + (ch+1)*32;
            #pragma unroll
            for (int tq = 0; tq < 4; ++tq)
                #pragma unroll
                for (int tc = 0; tc < 2; ++tc) {
                    const float* dp = dbase + (size_t)(q0 + tq*16 + g*4)*Ng + tc*16 + li;
                    f32x4 s; s[0]=dp[0]; s[1]=dp[Ng]; s[2]=dp[2*Ng]; s[3]=dp[3*Ng];
                    dnx[tq][tc] = s;
                }
        }
        // ---- S = Q.K^T + dist (dcur seeds accumulators) ----
        bf16x8 kbh[2], kbl[2];
        #pragma unroll
        for (int tc = 0; tc < 2; ++tc) {
            kbh[tc] = *(const bf16x8*)&Khi[cur][tc*16+li][g*8];
            kbl[tc] = *(const bf16x8*)&Klo[cur][tc*16+li][g*8];
        }
        f32x4 sacc[4][2];
        #pragma unroll
        for (int tq = 0; tq < 4; ++tq)
            #pragma unroll
            for (int tc = 0; tc < 2; ++tc) {
                sacc[tq][tc] = dcur[tq][tc];
                sacc[tq][tc] = __builtin_amdgcn_mfma_f32_16x16x32_bf16(qh[tq], kbh[tc], sacc[tq][tc], 0,0,0);
                sacc[tq][tc] = __builtin_amdgcn_mfma_f32_16x16x32_bf16(qh[tq], kbl[tc], sacc[tq][tc], 0,0,0);
                sacc[tq][tc] = __builtin_amdgcn_mfma_f32_16x16x32_bf16(ql[tq], kbh[tc], sacc[tq][tc], 0,0,0);
                sacc[tq][tc] = __builtin_amdgcn_mfma_f32_16x16x32_bf16(ql[tq], kbl[tc], sacc[tq][tc], 0,0,0);
            }
        // ---- softmax (batched) -> per-wave P staging ----
        #pragma unroll
        for (int tq = 0; tq < 4; ++tq)
            #pragma unroll
            for (int tc = 0; tc < 2; ++tc)
                #pragma unroll
                for (int r = 0; r < 4; ++r) {
                    float p = __expf(sacc[tq][tc][r] - 16.f);
                    lpart[tq][r] += p;
                    P32[w][tq*16 + g*4 + r][tc*16 + li] = packsplit(p);
                }
        // ---- PV ----
        bf16x8 vbh[2], vbl[2];
        #pragma unroll
        for (int td = 0; td < 2; ++td) {
            unsigned tmp[8];
            *(uint4*)&tmp[0] = *(const uint4*)&Vt[cur][td*16+li][g*8];
            *(uint4*)&tmp[4] = *(const uint4*)&Vt[cur][td*16+li][g*8+4];
            #pragma unroll
            for (int j=0;j<8;++j){ vbh[td][j]=(short)(tmp[j]&0xffff); vbl[td][j]=(short)(tmp[j]>>16); }
        }
        #pragma unroll
        for (int tq = 0; tq < 4; ++tq) {
            unsigned tmp[8];
            *(uint4*)&tmp[0] = *(const uint4*)&P32[w][tq*16+li][g*8];
            *(uint4*)&tmp[4] = *(const uint4*)&P32[w][tq*16+li][g*8+4];
            bf16x8 ph, pl;
            #pragma unroll
            for (int j=0;j<8;++j){ ph[j]=(short)(tmp[j]&0xffff); pl[j]=(short)(tmp[j]>>16); }
            #pragma unroll
            for (int td = 0; td < 2; ++td) {
                O[tq][td] = __builtin_amdgcn_mfma_f32_16x16x32_bf16(ph, vbh[td], O[tq][td], 0,0,0);
                O[tq][td] = __builtin_amdgcn_mfma_f32_16x16x32_bf16(ph, vbl[td], O[tq][td], 0,0,0);
                O[tq][td] = __builtin_amdgcn_mfma_f32_16x16x32_bf16(pl, vbh[td], O[tq][td], 0,0,0);
                O[tq][td] = __builtin_amdgcn_mfma_f32_16x16x32_bf16(pl, vbl[td], O[tq][td], 0,0,0);
            }
        }
        // ---- write-late staging into alternate buffer ----
        if (pref) {
            const int nb = cur ^ 1;
            unsigned ka[4] = {kvr.x,kvr.y,kvr.z,kvr.w};
            unsigned va[4] = {vvr.x,vvr.y,vvr.z,vvr.w};
            #pragma unroll
            for (int i = 0; i < 4; ++i) {
                Khi[nb][skey][se0+i] = (short)(ka[i] & 0xffff);
                Klo[nb][skey][se0+i] = (short)(ka[i] >> 16);
                Vt [nb][se0+i][skey] = va[i];
            }
        }
        __syncthreads();
    };

    #pragma unroll
    for (int ch8 = 0; ch8 < 8; ch8 += 2) {
        body(ch8,     dA, dB);
        body(ch8 + 1, dB, dA);
    }

    // epilogue: finish row sums, normalize, store packed AO [node][D]
    #pragma unroll
    for (int tq = 0; tq < 4; ++tq)
        #pragma unroll
        for (int r = 0; r < 4; ++r) {
            float s = lpart[tq][r];
            s += __shfl_xor(s, 1); s += __shfl_xor(s, 2);
            s += __shfl_xor(s, 4); s += __shfl_xor(s, 8);
            lpart[tq][r] = 1.f / s;
        }
    #pragma unroll
    for (int tq = 0; tq < 4; ++tq)
        #pragma unroll
        for (int td = 0; td < 2; ++td)
            #pragma unroll
            for (int r = 0; r < 4; ++r) {
                int q = q0 + tq*16 + g*4 + r;
                float val = O[tq][td][r] * lpart[tq][r];
                AOp[((size_t)b*Ng + q)*Dg + h*HDg + td*16 + li] = packsplit(val);
            }
}

// ---------------- K3: output projection (A from packed AO) -------------------
__global__ __launch_bounds__(256) void out_mm(
    const unsigned* __restrict__ aop,
    const short* __restrict__ bth, const short* __restrict__ btl,
    const float* __restrict__ bo, float* __restrict__ enc)
{
    __shared__ __align__(16) short lds[16384];
    const int tid = threadIdx.x;
    const int lane = tid & 63, w = tid >> 6;
    const int g = lane >> 4, li = lane & 15;
    const int wr = w >> 1, wc = w & 1;
    const int m0 = blockIdx.x * 128, n0 = blockIdx.y * 128;
    f32x4 acc[4][4];
    #pragma unroll
    for (int i = 0; i < 4; ++i)
        #pragma unroll
        for (int j = 0; j < 4; ++j) acc[i][j] = (f32x4){0.f,0.f,0.f,0.f};

    for (int k0 = 0; k0 < 256; k0 += 32) {
        #pragma unroll
        for (int it = 0; it < 2; ++it) {
            int chunk = it*256 + tid;
            int r = chunk >> 2, c = chunk & 3;
            size_t ga = (size_t)(m0 + r)*256 + k0 + c*8;
            size_t gb = (size_t)(n0 + r)*256 + k0 + c*8;
            uint4 p0 = *(const uint4*)(aop + ga);
            uint4 p1 = *(const uint4*)(aop + ga + 4);
            unsigned a[8] = {p0.x,p0.y,p0.z,p0.w,p1.x,p1.y,p1.z,p1.w};
            uint4 hw, lw;
            hw.x = (a[0]&0xffffu)|(a[1]<<16); lw.x = (a[0]>>16)|(a[1]&0xffff0000u);
            hw.y = (a[2]&0xffffu)|(a[3]<<16); lw.y = (a[2]>>16)|(a[3]&0xffff0000u);
            hw.z = (a[4]&0xffffu)|(a[5]<<16); lw.z = (a[4]>>16)|(a[5]&0xffff0000u);
            hw.w = (a[6]&0xffffu)|(a[7]<<16); lw.w = (a[6]>>16)|(a[7]&0xffff0000u);
            uint4 wh = *(const uint4*)(bth + gb);
            uint4 wl = *(const uint4*)(btl + gb);
            *(uint4*)&lds[        chunk*8] = hw;
            *(uint4*)&lds[ 4096 + chunk*8] = lw;
            *(uint4*)&lds[ 8192 + chunk*8] = wh;
            *(uint4*)&lds[12288 + chunk*8] = wl;
        }
        __syncthreads();
        bf16x8 ah[4], al[4], bh[4], bl[4];
        #pragma unroll
        for (int i = 0; i < 4; ++i) {
            int row = wr*64 + i*16 + li;
            ah[i] = *(const bf16x8*)&lds[       row*32 + g*8];
            al[i] = *(const bf16x8*)&lds[4096 + row*32 + g*8];
        }
        #pragma unroll
        for (int j = 0; j < 4; ++j) {
            int row = wc*64 + j*16 + li;
            bh[j] = *(const bf16x8*)&lds[ 8192 + row*32 + g*8];
            bl[j] = *(const bf16x8*)&lds[12288 + row*32 + g*8];
        }
        #pragma unroll
        for (int i = 0; i < 4; ++i)
            #pragma unroll
            for (int j = 0; j < 4; ++j) {
                acc[i][j] = __builtin_amdgcn_mfma_f32_16x16x32_bf16(ah[i], bh[j], acc[i][j], 0,0,0);
                acc[i][j] = __builtin_amdgcn_mfma_f32_16x16x32_bf16(ah[i], bl[j], acc[i][j], 0,0,0);
                acc[i][j] = __builtin_amdgcn_mfma_f32_16x16x32_bf16(al[i], bh[j], acc[i][j], 0,0,0);
                acc[i][j] = __builtin_amdgcn_mfma_f32_16x16x32_bf16(al[i], bl[j], acc[i][j], 0,0,0);
            }
        __syncthreads();
    }
    #pragma unroll
    for (int i = 0; i < 4; ++i)
        #pragma unroll
        for (int j = 0; j < 4; ++j)
            #pragma unroll
            for (int r = 0; r < 4; ++r) {
                int m = m0 + wr*64 + i*16 + g*4 + r;
                int c = n0 + wc*64 + j*16 + li;
                enc[(size_t)m*Dg + c] = acc[i][j][r] + bo[c];
            }
}

// ---------------- K4: pooling scores ----------------
__global__ __launch_bounds__(256) void score_kernel(
    const float* __restrict__ enc, const float* __restrict__ pw, float* __restrict__ score)
{
    int row  = blockIdx.x * 8 + (threadIdx.x >> 5);
    int lane = threadIdx.x & 31;
    const float* r = enc + (size_t)row * Dg;
    float s = 0.f;
    for (int d = lane; d < Dg; d += 32) s = fmaf(r[d], pw[d], s);
    #pragma unroll
    for (int off = 16; off > 0; off >>= 1) s += __shfl_xor(s, off);
    if (lane == 0) score[row] = s;
}

__global__ void norm_kernel(const float* __restrict__ pw, float* __restrict__ inv_norm)
{
    int t = threadIdx.x;
    float s = 0.f;
    for (int d = t; d < Dg; d += 64) s = fmaf(pw[d], pw[d], s);
    #pragma unroll
    for (int off = 32; off > 0; off >>= 1) s += __shfl_xor(s, off);
    if (t == 0) *inv_norm = 1.0f / sqrtf(s);
}

// ---------------- K5: per-graph exact top-K via rank count ----------------
__global__ __launch_bounds__(256) void topk_kernel(
    const float* __restrict__ score, float* __restrict__ vals, int* __restrict__ idxs,
    int* __restrict__ new_id, float* __restrict__ out_batch)
{
    __shared__ float sh[Ng];
    int bgr = blockIdx.x, t = threadIdx.x;
    float mine = score[(size_t)bgr * Ng + t];
    sh[t] = mine;
    __syncthreads();
    int cnt = 0;
    for (int j = 0; j < Ng; ++j) {
        float v = sh[j];
        cnt += (v > mine || (v == mine && j < t)) ? 1 : 0;
    }
    if (cnt < Kg) {
        int pos = bgr * Kg + cnt;
        vals[pos] = mine;
        idxs[pos] = t;
        new_id[bgr * Ng + t] = pos;
        out_batch[pos] = (float)bgr;
    } else {
        new_id[bgr * Ng + t] = SENT;
    }
}

// ---------------- K6: gather + tanh scale ----------------
__global__ __launch_bounds__(256) void subx_kernel(
    const float* __restrict__ enc, const float* __restrict__ vals,
    const int* __restrict__ idxs, const float* __restrict__ inv_norm,
    float* __restrict__ out_subx)
{
    int j    = blockIdx.x * 4 + (threadIdx.x >> 6);
    int lane = threadIdx.x & 63;
    int bgr  = j >> 7;
    int src  = bgr * Ng + idxs[j];
    float scale = tanhf(vals[j] * (*inv_norm));
    float4 v = reinterpret_cast<const float4*>(enc + (size_t)src * Dg)[lane];
    v.x *= scale; v.y *= scale; v.z *= scale; v.w *= scale;
    reinterpret_cast<float4*>(out_subx + (size_t)j * Dg)[lane] = v;
}

// ---------------- edge pipeline ----------------
__global__ __launch_bounds__(256) void edge_hist(
    const int* __restrict__ ei, const int* __restrict__ new_id, int* __restrict__ counts)
{
    int e = blockIdx.x * 256 + threadIdx.x;
    int r = new_id[ei[e]];
    int c = new_id[ei[Eg + e]];
    if (r != SENT && c != SENT) atomicAdd(&counts[r], 1);
}

// two-level scan: 256 threads x 64 elems each
__global__ __launch_bounds__(256) void scan_kernel(
    const int* __restrict__ counts, int* __restrict__ offsets)
{
    __shared__ int sums[256];
    int t = threadIdx.x;
    int base = t * 64;
    int s = 0;
    for (int i = 0; i < 64; ++i) s += counts[base + i];
    sums[t] = s;
    __syncthreads();
    for (int off = 1; off < 256; off <<= 1) {
        int add = (t >= off) ? sums[t - off] : 0;
        __syncthreads();
        sums[t] += add;
        __syncthreads();
    }
    int run = sums[t] - s;     // exclusive prefix of this segment
    for (int i = 0; i < 64; ++i) { offsets[base + i] = run; run += counts[base + i]; }
    if (t == 255) offsets[SENT] = run;
}

__global__ __launch_bounds__(256) void edge_scatter(
    const int* __restrict__ ei, const int* __restrict__ new_id,
    const int* __restrict__ offsets, int* __restrict__ cursor, int* __restrict__ bucket)
{
    int e = blockIdx.x * 256 + threadIdx.x;
    int r = new_id[ei[e]];
    int c = new_id[ei[Eg + e]];
    if (r != SENT && c != SENT) {
        int pos = offsets[r] + atomicAdd(&cursor[r], 1);
        bucket[pos] = c;
    }
}

__global__ __launch_bounds__(256) void edge_sort_emit(
    const int* __restrict__ offsets, int* bucket, float* __restrict__ out_edges)
{
    int r = blockIdx.x * 256 + threadIdx.x;
    int s = offsets[r], e = offsets[r + 1];
    for (int i = s + 1; i < e; ++i) {
        int key = bucket[i];
        int j = i - 1;
        while (j >= s && bucket[j] > key) { bucket[j+1] = bucket[j]; --j; }
        bucket[j+1] = key;
    }
    float rf = (float)r;
    for (int i = s; i < e; ++i) {
        out_edges[i]      = rf;
        out_edges[Eg + i] = (float)bucket[i];
    }
}

__global__ __launch_bounds__(256) void edge_fill(
    const int* __restrict__ offsets, float* __restrict__ out_edges)
{
    int p = blockIdx.x * 256 + threadIdx.x;
    if (p >= offsets[SENT]) {
        out_edges[p]      = (float)SENT;
        out_edges[Eg + p] = (float)SENT;
    }
}

// ---------------- launch ----------------
extern "C" void kernel_launch(void* const* d_in, const int* in_sizes, int n_in,
                              void* d_out, int out_size, void* d_ws, size_t ws_size,
                              hipStream_t stream)
{
    const float* x    = (const float*)d_in[0];
    const float* dist = (const float*)d_in[2];
    const int*   ei   = (const int*)d_in[3];
    const float* Wq = (const float*)d_in[5];
    const float* bq = (const float*)d_in[6];
    const float* Wk = (const float*)d_in[7];
    const float* bk = (const float*)d_in[8];
    const float* Wv = (const float*)d_in[9];
    const float* bv = (const float*)d_in[10];
    const float* Wo = (const float*)d_in[11];
    const float* bo = (const float*)d_in[12];
    const float* pw = (const float*)d_in[13];

    float* out       = (float*)d_out;
    float* enc_out   = out;                     // [B*N*D]
    float* subx_out  = out + 8388608;           // [B*K*D]
    float* edge_out  = out + 12582912;           // [2*E]
    float* batch_out = out + 13631488;           // [B*K]

    float* ws      = (float*)d_ws;
    unsigned* Qp   = (unsigned*)ws;              // 8,388,608 u32
    unsigned* Kp   = (unsigned*)(ws + 8388608);
    unsigned* Vp   = (unsigned*)(ws + 16777216);
    short* xh      = (short*)(ws + 25165824);    // 8,388,608 bf16
    short* xl      = (short*)(ws + 29360128);    // 8,388,608 bf16
    unsigned* AOp  = (unsigned*)xh;              // alias: spans xh+xl (33.5MB)
    short* WTh     = (short*)(ws + 33554432);    // 4*65536 bf16
    short* WTl     = (short*)(ws + 33685504);
    float* score   = ws + 33816576;              // 32768
    float* vals    = ws + 33849344;              // 16384
    int*   idxs    = (int*)(ws + 33865728);      // 16384
    int*   new_id  = (int*)(ws + 33882112);      // 32768
    int*   counts  = (int*)(ws + 33914880);      // 16384
    int*   offsets = (int*)(ws + 33931264);      // 16416
    int*   cursor  = (int*)(ws + 33947680);      // 16384
    float* inv_nm  = ws + 33964064;              // 32
    int*   bucket  = (int*)(ws + 33964096);      // 524288

    hipMemsetAsync(counts, 0, SENT * sizeof(int), stream);
    hipMemsetAsync(cursor, 0, SENT * sizeof(int), stream);

    split_x       <<<dim3(4096),               256, 0, stream>>>(x, xh, xl);
    wprep         <<<dim3(64),                 256, 0, stream>>>(Wq, Wk, Wv, Wo, WTh, WTl);
    norm_kernel   <<<dim3(1),                   64, 0, stream>>>(pw, inv_nm);
    qkv_mm        <<<dim3(BNg/128, Dg/128, 3), 256, 0, stream>>>(xh, xl, WTh, WTl, bq, bk, bv, Qp, Kp, Vp);
    attn_mfma     <<<dim3(Bg*Hg),              256, 0, stream>>>(Qp, Kp, Vp, dist, AOp);
    out_mm        <<<dim3(BNg/128, Dg/128),    256, 0, stream>>>(AOp, WTh + 3*65536, WTl + 3*65536, bo, enc_out);
    score_kernel  <<<dim3(BNg/8),              256, 0, stream>>>(enc_out, pw, score);
    topk_kernel   <<<dim3(Bg),                 256, 0, stream>>>(score, vals, idxs, new_id, batch_out);
    subx_kernel   <<<dim3((Bg*Kg)/4),          256, 0, stream>>>(enc_out, vals, idxs, inv_nm, subx_out);
    edge_hist     <<<dim3(Eg/256),             256, 0, stream>>>(ei, new_id, counts);
    scan_kernel   <<<dim3(1),                  256, 0, stream>>>(counts, offsets);
    edge_scatter  <<<dim3(Eg/256),             256, 0, stream>>>(ei, new_id, offsets, cursor, bucket);
    edge_sort_emit<<<dim3(SENT/256),           256, 0, stream>>>(offsets, bucket, edge_out);
    edge_fill     <<<dim3(Eg/256),             256, 0, stream>>>(offsets, edge_out);
    (void)in_sizes; (void)n_in; (void)out_size; (void)ws_size;
}

// Round 7
// 237.355 us; speedup vs baseline: 1.3017x; 1.3017x over previous
//
#include <hip/hip_runtime.h>
#include <math.h>

#define Bg   128
#define Ng   256
#define Dg   256
#define Hg   8
#define HDg  32
#define Eg   524288
#define Kg   128
#define BNg  32768
#define SENT 16384   // = Bg*Kg

using bf16x8 = __attribute__((ext_vector_type(8))) short;
using f32x4  = __attribute__((ext_vector_type(4))) float;

// split f32 -> bf16 hi (truncated) + bf16 lo (residual)
__device__ inline void split2(float x, short &h, short &l) {
    unsigned u = __float_as_uint(x);
    h = (short)(u >> 16);
    float hf = __uint_as_float(u & 0xffff0000u);
    float r = x - hf;
    l = (short)(__float_as_uint(r) >> 16);
}
// pack: low 16 = hi bf16, high 16 = lo bf16
__device__ inline unsigned packsplit(float x) {
    unsigned u = __float_as_uint(x);
    float hf = __uint_as_float(u & 0xffff0000u);
    float r = x - hf;
    unsigned lu = __float_as_uint(r);
    return (u >> 16) | (lu & 0xffff0000u);
}
__device__ inline unsigned pack2(short a, short b) {
    return (unsigned)(unsigned short)a | ((unsigned)(unsigned short)b << 16);
}

// ---------------- P1: split x into hi/lo bf16 ----------------
__global__ __launch_bounds__(256) void split_x(
    const float* __restrict__ x, short* __restrict__ xh, short* __restrict__ xl)
{
    size_t i = ((size_t)blockIdx.x * 256 + threadIdx.x) * 8;
    float4 a = *(const float4*)(x + i);
    float4 b = *(const float4*)(x + i + 4);
    float v[8] = {a.x,a.y,a.z,a.w,b.x,b.y,b.z,b.w};
    short h[8], l[8];
    #pragma unroll
    for (int j = 0; j < 8; ++j) split2(v[j], h[j], l[j]);
    uint4 uh, ul;
    uh.x = pack2(h[0],h[1]); uh.y = pack2(h[2],h[3]);
    uh.z = pack2(h[4],h[5]); uh.w = pack2(h[6],h[7]);
    ul.x = pack2(l[0],l[1]); ul.y = pack2(l[2],l[3]);
    ul.z = pack2(l[4],l[5]); ul.w = pack2(l[6],l[7]);
    *(uint4*)(xh + i) = uh;
    *(uint4*)(xl + i) = ul;
}

// ---------------- P2: transpose + split weights: WT[n][k] = W[k][n] ----------
__global__ __launch_bounds__(256) void wprep(
    const float* __restrict__ Wq, const float* __restrict__ Wk,
    const float* __restrict__ Wv, const float* __restrict__ Wo,
    short* __restrict__ WTh, short* __restrict__ WTl)
{
    __shared__ float t[64][65];
    const int bid = blockIdx.x;          // 0..63
    const int mat = bid >> 4;
    const int kt = (bid >> 2) & 3, nt = bid & 3;
    const float* W = (mat==0) ? Wq : (mat==1) ? Wk : (mat==2) ? Wv : Wo;
    const int tid = threadIdx.x;
    const int r = tid >> 2, c4 = tid & 3;
    #pragma unroll
    for (int i = 0; i < 4; ++i) {
        float4 v = *(const float4*)(W + (size_t)(kt*64 + r)*256 + nt*64 + c4*16 + i*4);
        t[r][c4*16 + i*4 + 0] = v.x; t[r][c4*16 + i*4 + 1] = v.y;
        t[r][c4*16 + i*4 + 2] = v.z; t[r][c4*16 + i*4 + 3] = v.w;
    }
    __syncthreads();
    const int n = r, k0 = c4 * 16;
    short hb[16], lb[16];
    #pragma unroll
    for (int i = 0; i < 16; ++i) split2(t[k0 + i][n], hb[i], lb[i]);
    size_t base = (size_t)mat*65536 + (size_t)(nt*64 + n)*256 + kt*64 + k0;
    uint4 uh0, uh1, ul0, ul1;
    uh0.x=pack2(hb[0],hb[1]);  uh0.y=pack2(hb[2],hb[3]);  uh0.z=pack2(hb[4],hb[5]);  uh0.w=pack2(hb[6],hb[7]);
    uh1.x=pack2(hb[8],hb[9]);  uh1.y=pack2(hb[10],hb[11]);uh1.z=pack2(hb[12],hb[13]);uh1.w=pack2(hb[14],hb[15]);
    ul0.x=pack2(lb[0],lb[1]);  ul0.y=pack2(lb[2],lb[3]);  ul0.z=pack2(lb[4],lb[5]);  ul0.w=pack2(lb[6],lb[7]);
    ul1.x=pack2(lb[8],lb[9]);  ul1.y=pack2(lb[10],lb[11]);ul1.z=pack2(lb[12],lb[13]);ul1.w=pack2(lb[14],lb[15]);
    *(uint4*)&WTh[base]     = uh0; *(uint4*)&WTh[base + 8] = uh1;
    *(uint4*)&WTl[base]     = ul0; *(uint4*)&WTl[base + 8] = ul1;
}

// ---------------- K1: QKV projection via 4-term split MFMA -------------------
// Outputs packed-split u32 (hi | lo<<16); Q pre-scaled by 1/sqrt(32).
__global__ __launch_bounds__(256) void qkv_mm(
    const short* __restrict__ xh, const short* __restrict__ xl,
    const short* __restrict__ WTh, const short* __restrict__ WTl,
    const float* __restrict__ bq, const float* __restrict__ bk, const float* __restrict__ bv,
    unsigned* __restrict__ Qp, unsigned* __restrict__ Kp, unsigned* __restrict__ Vp)
{
    const int z = blockIdx.z;
    const float* bias = (z==0) ? bq : (z==1) ? bk : bv;
    unsigned* out     = (z==0) ? Qp : (z==1) ? Kp : Vp;
    const float scale = (z==0) ? 0.17677669529663687f : 1.0f;
    const short* bth = WTh + (size_t)z * 65536;
    const short* btl = WTl + (size_t)z * 65536;
    __shared__ __align__(16) short lds[16384];   // Ah 0 | Al 4096 | Bh 8192 | Bl 12288
    const int tid = threadIdx.x;
    const int lane = tid & 63, w = tid >> 6;
    const int g = lane >> 4, li = lane & 15;
    const int wr = w >> 1, wc = w & 1;
    const int m0 = blockIdx.x * 128, n0 = blockIdx.y * 128;
    f32x4 acc[4][4];
    #pragma unroll
    for (int i = 0; i < 4; ++i)
        #pragma unroll
        for (int j = 0; j < 4; ++j) acc[i][j] = (f32x4){0.f,0.f,0.f,0.f};

    for (int k0 = 0; k0 < 256; k0 += 32) {
        #pragma unroll
        for (int it = 0; it < 2; ++it) {
            int chunk = it*256 + tid;
            int r = chunk >> 2, c = chunk & 3;
            size_t ga = (size_t)(m0 + r)*256 + k0 + c*8;
            size_t gb = (size_t)(n0 + r)*256 + k0 + c*8;
            uint4 vh = *(const uint4*)(xh + ga);
            uint4 vl = *(const uint4*)(xl + ga);
            uint4 wh = *(const uint4*)(bth + gb);
            uint4 wl = *(const uint4*)(btl + gb);
            *(uint4*)&lds[        chunk*8] = vh;
            *(uint4*)&lds[ 4096 + chunk*8] = vl;
            *(uint4*)&lds[ 8192 + chunk*8] = wh;
            *(uint4*)&lds[12288 + chunk*8] = wl;
        }
        __syncthreads();
        bf16x8 ah[4], al[4], bh[4], bl[4];
        #pragma unroll
        for (int i = 0; i < 4; ++i) {
            int row = wr*64 + i*16 + li;
            ah[i] = *(const bf16x8*)&lds[       row*32 + g*8];
            al[i] = *(const bf16x8*)&lds[4096 + row*32 + g*8];
        }
        #pragma unroll
        for (int j = 0; j < 4; ++j) {
            int row = wc*64 + j*16 + li;
            bh[j] = *(const bf16x8*)&lds[ 8192 + row*32 + g*8];
            bl[j] = *(const bf16x8*)&lds[12288 + row*32 + g*8];
        }
        #pragma unroll
        for (int i = 0; i < 4; ++i)
            #pragma unroll
            for (int j = 0; j < 4; ++j) {
                acc[i][j] = __builtin_amdgcn_mfma_f32_16x16x32_bf16(ah[i], bh[j], acc[i][j], 0,0,0);
                acc[i][j] = __builtin_amdgcn_mfma_f32_16x16x32_bf16(ah[i], bl[j], acc[i][j], 0,0,0);
                acc[i][j] = __builtin_amdgcn_mfma_f32_16x16x32_bf16(al[i], bh[j], acc[i][j], 0,0,0);
                acc[i][j] = __builtin_amdgcn_mfma_f32_16x16x32_bf16(al[i], bl[j], acc[i][j], 0,0,0);
            }
        __syncthreads();
    }
    #pragma unroll
    for (int i = 0; i < 4; ++i)
        #pragma unroll
        for (int j = 0; j < 4; ++j)
            #pragma unroll
            for (int r = 0; r < 4; ++r) {
                int m = m0 + wr*64 + i*16 + g*4 + r;
                int c = n0 + wc*64 + j*16 + li;
                int b = m >> 8, nn = m & 255;
                int h = c >> 5, hd = c & 31;
                float val = (acc[i][j][r] + bias[c]) * scale;
                out[((size_t)(b*Hg + h)*Ng + nn)*HDg + hd] = packsplit(val);
            }
}

// ---------------- K2: MFMA flash attention (r4 structure + XCD remap) -------
// Packed-split inputs; batched per-wave P; K/V reg prefetch with write-late;
// dist seeds MFMA accumulators (L2-hot via remap). One barrier per chunk.
__global__ __launch_bounds__(256, 2) void attn_mfma(
    const unsigned* __restrict__ Qp, const unsigned* __restrict__ Kp,
    const unsigned* __restrict__ Vp, const float* __restrict__ dist,
    unsigned* __restrict__ AOp)
{
    __shared__ short    Khi[2][32][40];     //  5120 B
    __shared__ short    Klo[2][32][40];     //  5120 B
    __shared__ unsigned Vt [2][32][36];     //  9216 B  [buf][d][key] packed
    __shared__ unsigned P32[4][64][36];     // 36864 B  per-wave P (batched)

    // XCD-aware remap: XCD = blockIdx.x % 8 (round-robin dispatch). Place all
    // 8 heads of graph b on one XCD, adjacent in its local sequence, so
    // dist[b] (256KB) is fetched once into that XCD's L2.
    const int i0 = blockIdx.x;
    const int xcd = i0 & 7;
    const int m_  = i0 >> 3;
    const int h   = m_ & 7;
    const int b   = (m_ >> 3) * 8 + xcd;
    const int bh  = b * 8 + h;

    const int tid = threadIdx.x;
    const int w = tid >> 6;
    const int lane = tid & 63;
    const int g = lane >> 4;
    const int li = lane & 15;
    const int q0 = w * 64;
    const int skey = tid >> 3, se0 = (tid & 7) * 4;   // staging coords
    const float* dall = dist + (size_t)b*Ng*Ng;

    // Q fragments (already scaled + split in qkv_mm)
    bf16x8 qh[4], ql[4];
    #pragma unroll
    for (int tq = 0; tq < 4; ++tq) {
        const unsigned* qp = Qp + ((size_t)bh * Ng + q0 + tq*16 + li) * HDg + g*8;
        uint4 u0 = *(const uint4*)qp;
        uint4 u1 = *(const uint4*)(qp + 4);
        unsigned uu[8] = {u0.x,u0.y,u0.z,u0.w,u1.x,u1.y,u1.z,u1.w};
        #pragma unroll
        for (int j = 0; j < 8; ++j) {
            qh[tq][j] = (short)(uu[j] & 0xffff);
            ql[tq][j] = (short)(uu[j] >> 16);
        }
    }

    // stage chunk 0 into buf 0
    {
        uint4 kv = *(const uint4*)(Kp + ((size_t)bh*Ng + skey) * HDg + se0);
        uint4 vv = *(const uint4*)(Vp + ((size_t)bh*Ng + skey) * HDg + se0);
        unsigned ka[4] = {kv.x,kv.y,kv.z,kv.w};
        unsigned va[4] = {vv.x,vv.y,vv.z,vv.w};
        #pragma unroll
        for (int i = 0; i < 4; ++i) {
            Khi[0][skey][se0+i] = (short)(ka[i] & 0xffff);
            Klo[0][skey][se0+i] = (short)(ka[i] >> 16);
            Vt [0][se0+i][skey] = va[i];
        }
    }
    __syncthreads();

    f32x4 O[4][2];
    #pragma unroll
    for (int tq=0;tq<4;++tq)
        #pragma unroll
        for (int td=0;td<2;++td) O[tq][td] = (f32x4){0.f,0.f,0.f,0.f};
    float lpart[4][4] = {};

    for (int ch = 0; ch < 8; ++ch) {
        const int cur = ch & 1;
        const bool pref = (ch < 7);
        uint4 kvr, vvr;
        if (pref) {
            // issue next-chunk K/V loads EARLY (8 VGPRs); written after compute
            kvr = *(const uint4*)(Kp + ((size_t)bh*Ng + (ch+1)*32 + skey) * HDg + se0);
            vvr = *(const uint4*)(Vp + ((size_t)bh*Ng + (ch+1)*32 + skey) * HDg + se0);
        }
        // S = Q.K^T + dist; dist seeds accumulators (L2-hot after remap)
        f32x4 sacc[4][2];
        const float* dbase = dall + ch*32;
        #pragma unroll
        for (int tq = 0; tq < 4; ++tq)
            #pragma unroll
            for (int tc = 0; tc < 2; ++tc) {
                const float* dp = dbase + (size_t)(q0 + tq*16 + g*4)*Ng + tc*16 + li;
                f32x4 s; s[0]=dp[0]; s[1]=dp[Ng]; s[2]=dp[2*Ng]; s[3]=dp[3*Ng];
                sacc[tq][tc] = s;
            }
        bf16x8 kbh[2], kbl[2];
        #pragma unroll
        for (int tc = 0; tc < 2; ++tc) {
            kbh[tc] = *(const bf16x8*)&Khi[cur][tc*16+li][g*8];
            kbl[tc] = *(const bf16x8*)&Klo[cur][tc*16+li][g*8];
        }
        #pragma unroll
        for (int tq = 0; tq < 4; ++tq)
            #pragma unroll
            for (int tc = 0; tc < 2; ++tc) {
                sacc[tq][tc] = __builtin_amdgcn_mfma_f32_16x16x32_bf16(qh[tq], kbh[tc], sacc[tq][tc], 0,0,0);
                sacc[tq][tc] = __builtin_amdgcn_mfma_f32_16x16x32_bf16(qh[tq], kbl[tc], sacc[tq][tc], 0,0,0);
                sacc[tq][tc] = __builtin_amdgcn_mfma_f32_16x16x32_bf16(ql[tq], kbh[tc], sacc[tq][tc], 0,0,0);
                sacc[tq][tc] = __builtin_amdgcn_mfma_f32_16x16x32_bf16(ql[tq], kbl[tc], sacc[tq][tc], 0,0,0);
            }
        // softmax (batched) -> per-wave P staging
        #pragma unroll
        for (int tq = 0; tq < 4; ++tq)
            #pragma unroll
            for (int tc = 0; tc < 2; ++tc)
                #pragma unroll
                for (int r = 0; r < 4; ++r) {
                    float p = __expf(sacc[tq][tc][r] - 16.f);
                    lpart[tq][r] += p;
                    P32[w][tq*16 + g*4 + r][tc*16 + li] = packsplit(p);
                }
        // PV
        bf16x8 vbh[2], vbl[2];
        #pragma unroll
        for (int td = 0; td < 2; ++td) {
            unsigned tmp[8];
            *(uint4*)&tmp[0] = *(const uint4*)&Vt[cur][td*16+li][g*8];
            *(uint4*)&tmp[4] = *(const uint4*)&Vt[cur][td*16+li][g*8+4];
            #pragma unroll
            for (int j=0;j<8;++j){ vbh[td][j]=(short)(tmp[j]&0xffff); vbl[td][j]=(short)(tmp[j]>>16); }
        }
        #pragma unroll
        for (int tq = 0; tq < 4; ++tq) {
            unsigned tmp[8];
            *(uint4*)&tmp[0] = *(const uint4*)&P32[w][tq*16+li][g*8];
            *(uint4*)&tmp[4] = *(const uint4*)&P32[w][tq*16+li][g*8+4];
            bf16x8 ph, pl;
            #pragma unroll
            for (int j=0;j<8;++j){ ph[j]=(short)(tmp[j]&0xffff); pl[j]=(short)(tmp[j]>>16); }
            #pragma unroll
            for (int td = 0; td < 2; ++td) {
                O[tq][td] = __builtin_amdgcn_mfma_f32_16x16x32_bf16(ph, vbh[td], O[tq][td], 0,0,0);
                O[tq][td] = __builtin_amdgcn_mfma_f32_16x16x32_bf16(ph, vbl[td], O[tq][td], 0,0,0);
                O[tq][td] = __builtin_amdgcn_mfma_f32_16x16x32_bf16(pl, vbh[td], O[tq][td], 0,0,0);
                O[tq][td] = __builtin_amdgcn_mfma_f32_16x16x32_bf16(pl, vbl[td], O[tq][td], 0,0,0);
            }
        }
        // write-late staging into alternate buffer
        if (pref) {
            const int nb = cur ^ 1;
            unsigned ka[4] = {kvr.x,kvr.y,kvr.z,kvr.w};
            unsigned va[4] = {vvr.x,vvr.y,vvr.z,vvr.w};
            #pragma unroll
            for (int i = 0; i < 4; ++i) {
                Khi[nb][skey][se0+i] = (short)(ka[i] & 0xffff);
                Klo[nb][skey][se0+i] = (short)(ka[i] >> 16);
                Vt [nb][se0+i][skey] = va[i];
            }
        }
        __syncthreads();
    }
    // epilogue: finish row sums, normalize, store packed AO [node][D]
    #pragma unroll
    for (int tq = 0; tq < 4; ++tq)
        #pragma unroll
        for (int r = 0; r < 4; ++r) {
            float s = lpart[tq][r];
            s += __shfl_xor(s, 1); s += __shfl_xor(s, 2);
            s += __shfl_xor(s, 4); s += __shfl_xor(s, 8);
            lpart[tq][r] = 1.f / s;
        }
    #pragma unroll
    for (int tq = 0; tq < 4; ++tq)
        #pragma unroll
        for (int td = 0; td < 2; ++td)
            #pragma unroll
            for (int r = 0; r < 4; ++r) {
                int q = q0 + tq*16 + g*4 + r;
                float val = O[tq][td][r] * lpart[tq][r];
                AOp[((size_t)b*Ng + q)*Dg + h*HDg + td*16 + li] = packsplit(val);
            }
}

// ---------------- K3: output projection (A from packed AO) -------------------
__global__ __launch_bounds__(256) void out_mm(
    const unsigned* __restrict__ aop,
    const short* __restrict__ bth, const short* __restrict__ btl,
    const float* __restrict__ bo, float* __restrict__ enc)
{
    __shared__ __align__(16) short lds[16384];
    const int tid = threadIdx.x;
    const int lane = tid & 63, w = tid >> 6;
    const int g = lane >> 4, li = lane & 15;
    const int wr = w >> 1, wc = w & 1;
    const int m0 = blockIdx.x * 128, n0 = blockIdx.y * 128;
    f32x4 acc[4][4];
    #pragma unroll
    for (int i = 0; i < 4; ++i)
        #pragma unroll
        for (int j = 0; j < 4; ++j) acc[i][j] = (f32x4){0.f,0.f,0.f,0.f};

    for (int k0 = 0; k0 < 256; k0 += 32) {
        #pragma unroll
        for (int it = 0; it < 2; ++it) {
            int chunk = it*256 + tid;
            int r = chunk >> 2, c = chunk & 3;
            size_t ga = (size_t)(m0 + r)*256 + k0 + c*8;
            size_t gb = (size_t)(n0 + r)*256 + k0 + c*8;
            uint4 p0 = *(const uint4*)(aop + ga);
            uint4 p1 = *(const uint4*)(aop + ga + 4);
            unsigned a[8] = {p0.x,p0.y,p0.z,p0.w,p1.x,p1.y,p1.z,p1.w};
            uint4 hw, lw;
            hw.x = (a[0]&0xffffu)|(a[1]<<16); lw.x = (a[0]>>16)|(a[1]&0xffff0000u);
            hw.y = (a[2]&0xffffu)|(a[3]<<16); lw.y = (a[2]>>16)|(a[3]&0xffff0000u);
            hw.z = (a[4]&0xffffu)|(a[5]<<16); lw.z = (a[4]>>16)|(a[5]&0xffff0000u);
            hw.w = (a[6]&0xffffu)|(a[7]<<16); lw.w = (a[6]>>16)|(a[7]&0xffff0000u);
            uint4 wh = *(const uint4*)(bth + gb);
            uint4 wl = *(const uint4*)(btl + gb);
            *(uint4*)&lds[        chunk*8] = hw;
            *(uint4*)&lds[ 4096 + chunk*8] = lw;
            *(uint4*)&lds[ 8192 + chunk*8] = wh;
            *(uint4*)&lds[12288 + chunk*8] = wl;
        }
        __syncthreads();
        bf16x8 ah[4], al[4], bh[4], bl[4];
        #pragma unroll
        for (int i = 0; i < 4; ++i) {
            int row = wr*64 + i*16 + li;
            ah[i] = *(const bf16x8*)&lds[       row*32 + g*8];
            al[i] = *(const bf16x8*)&lds[4096 + row*32 + g*8];
        }
        #pragma unroll
        for (int j = 0; j < 4; ++j) {
            int row = wc*64 + j*16 + li;
            bh[j] = *(const bf16x8*)&lds[ 8192 + row*32 + g*8];
            bl[j] = *(const bf16x8*)&lds[12288 + row*32 + g*8];
        }
        #pragma unroll
        for (int i = 0; i < 4; ++i)
            #pragma unroll
            for (int j = 0; j < 4; ++j) {
                acc[i][j] = __builtin_amdgcn_mfma_f32_16x16x32_bf16(ah[i], bh[j], acc[i][j], 0,0,0);
                acc[i][j] = __builtin_amdgcn_mfma_f32_16x16x32_bf16(ah[i], bl[j], acc[i][j], 0,0,0);
                acc[i][j] = __builtin_amdgcn_mfma_f32_16x16x32_bf16(al[i], bh[j], acc[i][j], 0,0,0);
                acc[i][j] = __builtin_amdgcn_mfma_f32_16x16x32_bf16(al[i], bl[j], acc[i][j], 0,0,0);
            }
        __syncthreads();
    }
    #pragma unroll
    for (int i = 0; i < 4; ++i)
        #pragma unroll
        for (int j = 0; j < 4; ++j)
            #pragma unroll
            for (int r = 0; r < 4; ++r) {
                int m = m0 + wr*64 + i*16 + g*4 + r;
                int c = n0 + wc*64 + j*16 + li;
                enc[(size_t)m*Dg + c] = acc[i][j][r] + bo[c];
            }
}

// ---------------- K4: pooling scores ----------------
__global__ __launch_bounds__(256) void score_kernel(
    const float* __restrict__ enc, const float* __restrict__ pw, float* __restrict__ score)
{
    int row  = blockIdx.x * 8 + (threadIdx.x >> 5);
    int lane = threadIdx.x & 31;
    const float* r = enc + (size_t)row * Dg;
    float s = 0.f;
    for (int d = lane; d < Dg; d += 32) s = fmaf(r[d], pw[d], s);
    #pragma unroll
    for (int off = 16; off > 0; off >>= 1) s += __shfl_xor(s, off);
    if (lane == 0) score[row] = s;
}

__global__ void norm_kernel(const float* __restrict__ pw, float* __restrict__ inv_norm)
{
    int t = threadIdx.x;
    float s = 0.f;
    for (int d = t; d < Dg; d += 64) s = fmaf(pw[d], pw[d], s);
    #pragma unroll
    for (int off = 32; off > 0; off >>= 1) s += __shfl_xor(s, off);
    if (t == 0) *inv_norm = 1.0f / sqrtf(s);
}

// ---------------- K5: per-graph exact top-K via rank count ----------------
__global__ __launch_bounds__(256) void topk_kernel(
    const float* __restrict__ score, float* __restrict__ vals, int* __restrict__ idxs,
    int* __restrict__ new_id, float* __restrict__ out_batch)
{
    __shared__ float sh[Ng];
    int bgr = blockIdx.x, t = threadIdx.x;
    float mine = score[(size_t)bgr * Ng + t];
    sh[t] = mine;
    __syncthreads();
    int cnt = 0;
    for (int j = 0; j < Ng; ++j) {
        float v = sh[j];
        cnt += (v > mine || (v == mine && j < t)) ? 1 : 0;
    }
    if (cnt < Kg) {
        int pos = bgr * Kg + cnt;
        vals[pos] = mine;
        idxs[pos] = t;
        new_id[bgr * Ng + t] = pos;
        out_batch[pos] = (float)bgr;
    } else {
        new_id[bgr * Ng + t] = SENT;
    }
}

// ---------------- K6: gather + tanh scale ----------------
__global__ __launch_bounds__(256) void subx_kernel(
    const float* __restrict__ enc, const float* __restrict__ vals,
    const int* __restrict__ idxs, const float* __restrict__ inv_norm,
    float* __restrict__ out_subx)
{
    int j    = blockIdx.x * 4 + (threadIdx.x >> 6);
    int lane = threadIdx.x & 63;
    int bgr  = j >> 7;
    int src  = bgr * Ng + idxs[j];
    float scale = tanhf(vals[j] * (*inv_norm));
    float4 v = reinterpret_cast<const float4*>(enc + (size_t)src * Dg)[lane];
    v.x *= scale; v.y *= scale; v.z *= scale; v.w *= scale;
    reinterpret_cast<float4*>(out_subx + (size_t)j * Dg)[lane] = v;
}

// ---------------- edge pipeline ----------------
__global__ __launch_bounds__(256) void edge_hist(
    const int* __restrict__ ei, const int* __restrict__ new_id, int* __restrict__ counts)
{
    int e = blockIdx.x * 256 + threadIdx.x;
    int r = new_id[ei[e]];
    int c = new_id[ei[Eg + e]];
    if (r != SENT && c != SENT) atomicAdd(&counts[r], 1);
}

// two-level scan: 256 threads x 64 elems each
__global__ __launch_bounds__(256) void scan_kernel(
    const int* __restrict__ counts, int* __restrict__ offsets)
{
    __shared__ int sums[256];
    int t = threadIdx.x;
    int base = t * 64;
    int s = 0;
    for (int i = 0; i < 64; ++i) s += counts[base + i];
    sums[t] = s;
    __syncthreads();
    for (int off = 1; off < 256; off <<= 1) {
        int add = (t >= off) ? sums[t - off] : 0;
        __syncthreads();
        sums[t] += add;
        __syncthreads();
    }
    int run = sums[t] - s;     // exclusive prefix of this segment
    for (int i = 0; i < 64; ++i) { offsets[base + i] = run; run += counts[base + i]; }
    if (t == 255) offsets[SENT] = run;
}

__global__ __launch_bounds__(256) void edge_scatter(
    const int* __restrict__ ei, const int* __restrict__ new_id,
    const int* __restrict__ offsets, int* __restrict__ cursor, int* __restrict__ bucket)
{
    int e = blockIdx.x * 256 + threadIdx.x;
    int r = new_id[ei[e]];
    int c = new_id[ei[Eg + e]];
    if (r != SENT && c != SENT) {
        int pos = offsets[r] + atomicAdd(&cursor[r], 1);
        bucket[pos] = c;
    }
}

__global__ __launch_bounds__(256) void edge_sort_emit(
    const int* __restrict__ offsets, int* bucket, float* __restrict__ out_edges)
{
    int r = blockIdx.x * 256 + threadIdx.x;
    int s = offsets[r], e = offsets[r + 1];
    for (int i = s + 1; i < e; ++i) {
        int key = bucket[i];
        int j = i - 1;
        while (j >= s && bucket[j] > key) { bucket[j+1] = bucket[j]; --j; }
        bucket[j+1] = key;
    }
    float rf = (float)r;
    for (int i = s; i < e; ++i) {
        out_edges[i]      = rf;
        out_edges[Eg + i] = (float)bucket[i];
    }
}

__global__ __launch_bounds__(256) void edge_fill(
    const int* __restrict__ offsets, float* __restrict__ out_edges)
{
    int p = blockIdx.x * 256 + threadIdx.x;
    if (p >= offsets[SENT]) {
        out_edges[p]      = (float)SENT;
        out_edges[Eg + p] = (float)SENT;
    }
}

// ---------------- launch ----------------
extern "C" void kernel_launch(void* const* d_in, const int* in_sizes, int n_in,
                              void* d_out, int out_size, void* d_ws, size_t ws_size,
                              hipStream_t stream)
{
    const float* x    = (const float*)d_in[0];
    const float* dist = (const float*)d_in[2];
    const int*   ei   = (const int*)d_in[3];
    const float* Wq = (const float*)d_in[5];
    const float* bq = (const float*)d_in[6];
    const float* Wk = (const float*)d_in[7];
    const float* bk = (const float*)d_in[8];
    const float* Wv = (const float*)d_in[9];
    const float* bv = (const float*)d_in[10];
    const float* Wo = (const float*)d_in[11];
    const float* bo = (const float*)d_in[12];
    const float* pw = (const float*)d_in[13];

    float* out       = (float*)d_out;
    float* enc_out   = out;                     // [B*N*D]
    float* subx_out  = out + 8388608;           // [B*K*D]
    float* edge_out  = out + 12582912;          // [2*E]
    float* batch_out = out + 13631488;          // [B*K]

    float* ws      = (float*)d_ws;
    unsigned* Qp   = (unsigned*)ws;              // 8,388,608 u32
    unsigned* Kp   = (unsigned*)(ws + 8388608);
    unsigned* Vp   = (unsigned*)(ws + 16777216);
    short* xh      = (short*)(ws + 25165824);    // 8,388,608 bf16
    short* xl      = (short*)(ws + 29360128);    // 8,388,608 bf16
    unsigned* AOp  = (unsigned*)xh;              // alias: spans xh+xl (33.5MB)
    short* WTh     = (short*)(ws + 33554432);    // 4*65536 bf16
    short* WTl     = (short*)(ws + 33685504);
    float* score   = ws + 33816576;              // 32768
    float* vals    = ws + 33849344;              // 16384
    int*   idxs    = (int*)(ws + 33865728);      // 16384
    int*   new_id  = (int*)(ws + 33882112);      // 32768
    int*   counts  = (int*)(ws + 33914880);      // 16384
    int*   offsets = (int*)(ws + 33931264);      // 16416
    int*   cursor  = (int*)(ws + 33947680);      // 16384
    float* inv_nm  = ws + 33964064;              // 32
    int*   bucket  = (int*)(ws + 33964096);      // 524288

    hipMemsetAsync(counts, 0, SENT * sizeof(int), stream);
    hipMemsetAsync(cursor, 0, SENT * sizeof(int), stream);

    split_x       <<<dim3(4096),               256, 0, stream>>>(x, xh, xl);
    wprep         <<<dim3(64),                 256, 0, stream>>>(Wq, Wk, Wv, Wo, WTh, WTl);
    norm_kernel   <<<dim3(1),                   64, 0, stream>>>(pw, inv_nm);
    qkv_mm        <<<dim3(BNg/128, Dg/128, 3), 256, 0, stream>>>(xh, xl, WTh, WTl, bq, bk, bv, Qp, Kp, Vp);
    attn_mfma     <<<dim3(Bg*Hg),              256, 0, stream>>>(Qp, Kp, Vp, dist, AOp);
    out_mm        <<<dim3(BNg/128, Dg/128),    256, 0, stream>>>(AOp, WTh + 3*65536, WTl + 3*65536, bo, enc_out);
    score_kernel  <<<dim3(BNg/8),              256, 0, stream>>>(enc_out, pw, score);
    topk_kernel   <<<dim3(Bg),                 256, 0, stream>>>(score, vals, idxs, new_id, batch_out);
    subx_kernel   <<<dim3((Bg*Kg)/4),          256, 0, stream>>>(enc_out, vals, idxs, inv_nm, subx_out);
    edge_hist     <<<dim3(Eg/256),             256, 0, stream>>>(ei, new_id, counts);
    scan_kernel   <<<dim3(1),                  256, 0, stream>>>(counts, offsets);
    edge_scatter  <<<dim3(Eg/256),             256, 0, stream>>>(ei, new_id, offsets, cursor, bucket);
    edge_sort_emit<<<dim3(SENT/256),           256, 0, stream>>>(offsets, bucket, edge_out);
    edge_fill     <<<dim3(Eg/256),             256, 0, stream>>>(offsets, edge_out);
    (void)in_sizes; (void)n_in; (void)out_size; (void)ws_size;
}